// Round 4
// baseline (517.129 us; speedup 1.0000x reference)
//
#include <hip/hip_runtime.h>
#include <cstddef>

#define NB 16384
#define NGRP 16
#define AS 1160   // act batch stride in halves (16*72 + 8 pad)

typedef __attribute__((ext_vector_type(8))) _Float16 half8;
typedef __attribute__((ext_vector_type(4))) _Float16 half4;
typedef __attribute__((ext_vector_type(4))) float f32x4;
typedef __attribute__((ext_vector_type(2))) float f32x2;
typedef __attribute__((ext_vector_type(16))) float f32x16;

// ---- ws float offsets ----
#define OFF_W1T 0                      // 12*64
#define OFF_SC1 768
#define OFF_SH1 832
#define OFF_SC2 896
#define OFF_SH2 960
#define OFF_SC3 1024
#define OFF_SH3 1088
#define OFF_PB  1152                   // 4*16
#define OFF_PBB 1216                   // 16
#define OFF_CO  1232                   // 16*64 -> 2256
#define OFF_W2H 2304                   // 20*2*64*8 halves = 10240 floats
#define OFF_W2L 12544                  // 10240 floats
#define OFF_W3H 22784                  // 28*2*64*8 halves = 14336 floats
#define OFF_W3L 37120                  // 14336 floats
#define OFF_SF  51456                  // NB*64
#define OFF_H   (51456 + NB*64)        // NB*16

static __device__ __forceinline__ f32x16 mfma16(half8 a, half8 b, f32x16 c) {
  return __builtin_amdgcn_mfma_f32_32x32x16_f16(a, b, c, 0, 0, 0);
}

// ============================ prep ============================
__global__ __launch_bounds__(256) void prep_kernel(
    const float* __restrict__ conv1_w, const float* __restrict__ conv1_b,
    const float* __restrict__ conv2_w, const float* __restrict__ conv2_b,
    const float* __restrict__ conv3_w, const float* __restrict__ conv3_b,
    const float* __restrict__ bn1_g, const float* __restrict__ bn1_b,
    const float* __restrict__ bn2_g, const float* __restrict__ bn2_b,
    const float* __restrict__ bn3_g, const float* __restrict__ bn3_b,
    const float* __restrict__ proj_w, const float* __restrict__ proj_b,
    const float* __restrict__ A, const float* __restrict__ Bm,
    const float* __restrict__ Cm, const float* __restrict__ out_w,
    float* __restrict__ ws)
{
  int tid = blockIdx.x * blockDim.x + threadIdx.x;
  int nt = gridDim.x * blockDim.x;
  const float s = rsqrtf(1.0f + 1e-5f);

  for (int i = tid; i < 64*12; i += nt) {       // w1t[(c*3+k)*64+o]
    int o = i & 63, rk = i >> 6;
    ws[OFF_W1T + i] = conv1_w[o*12 + rk];
  }
  for (int o = tid; o < 64; o += nt) {
    float s1 = bn1_g[o]*s, s2 = bn2_g[o]*s, s3 = bn3_g[o]*s;
    ws[OFF_SC1+o] = s1; ws[OFF_SH1+o] = s1*conv1_b[o] + bn1_b[o];
    ws[OFF_SC2+o] = s2; ws[OFF_SH2+o] = s2*conv2_b[o] + bn2_b[o];
    ws[OFF_SC3+o] = s3; ws[OFF_SH3+o] = s3*conv3_b[o] + bn3_b[o];
  }
  // conv2 A-fragments for 32x32x16, k = tap*64 + ic (tap-major), hi/lo split.
  {
    _Float16* w2h = (_Float16*)(ws + OFF_W2H);
    _Float16* w2l = (_Float16*)(ws + OFF_W2L);
    for (int i = tid; i < 20*2*64; i += nt) {
      int lane = i & 63, ot = (i >> 6) & 1, sk = i >> 7;
      int tap = sk >> 2, ic0 = (sk & 3)*16 + (lane >> 5)*8;
      int o = ot*32 + (lane & 31);
      #pragma unroll
      for (int j = 0; j < 8; ++j) {
        float w = conv2_w[o*320 + (ic0 + j)*5 + tap];
        _Float16 hi = (_Float16)w;
        w2h[(size_t)i*8 + j] = hi;
        w2l[(size_t)i*8 + j] = (_Float16)(w - (float)hi);
      }
    }
  }
  {
    _Float16* w3h = (_Float16*)(ws + OFF_W3H);
    _Float16* w3l = (_Float16*)(ws + OFF_W3L);
    for (int i = tid; i < 28*2*64; i += nt) {
      int lane = i & 63, ot = (i >> 6) & 1, sk = i >> 7;
      int tap = sk >> 2, ic0 = (sk & 3)*16 + (lane >> 5)*8;
      int o = ot*32 + (lane & 31);
      #pragma unroll
      for (int j = 0; j < 8; ++j) {
        float w = conv3_w[o*448 + (ic0 + j)*7 + tap];
        _Float16 hi = (_Float16)w;
        w3h[(size_t)i*8 + j] = hi;
        w3l[(size_t)i*8 + j] = (_Float16)(w - (float)hi);
      }
    }
  }
  // PB[c][j] = sum_m proj_w[c][m]*Bm[m][j]
  for (int i = tid; i < 64; i += nt) {
    int c = i >> 4, j = i & 15;
    float acc = 0.f;
    for (int m = 0; m < 64; ++m) acc += proj_w[c*64+m]*Bm[m*16+j];
    ws[OFF_PB + i] = acc;
  }
  for (int j = tid; j < 16; j += nt) {
    float acc = 0.f;
    for (int m = 0; m < 64; ++m) acc += proj_b[m]*Bm[m*16+j];
    ws[OFF_PBB + j] = acc;
  }
  // CO[j][o] = sum_m Cm[j][m]*out_w[m][o]
  for (int i = tid; i < 16*64; i += nt) {
    int j = i >> 6, o = i & 63;
    float acc = 0.f;
    for (int m = 0; m < 64; ++m) acc += Cm[j*64+m]*out_w[m*64+o];
    ws[OFF_CO + i] = acc;
  }
}

// ============================ conv stack ============================
// Roles: waves 0-1 = c2 (w2 hi+lo in regs, ot=wid, 2 pairs);
//        waves 2-5 = c3 (w3 hi in regs, lo from LDS; (ot,pair) split; +conv1).
// Pipeline per iter: Seg1: c3 conv1(g), c2 conv2-pair1(g-1);
//                    Seg2: c2 conv2-pair0(g), c3 conv3(g-1) -> sf.
__global__ __launch_bounds__(384, 2) void conv_kernel(
    const float* __restrict__ x, const float* __restrict__ wsr,
    float* __restrict__ sfp)
{
  __shared__ __align__(16) _Float16 a1h[2][4*AS];
  __shared__ __align__(16) _Float16 a1l[2][4*AS];
  __shared__ __align__(16) _Float16 a2h[2][4*AS];
  __shared__ __align__(16) _Float16 a2l[2][4*AS];
  __shared__ __align__(16) _Float16 w3ls[28*2*64*8];   // 57344 B

  const int tid = threadIdx.x;
  const int lane = tid & 63;
  const int wid = tid >> 6;
  const bool isC2 = (wid < 2);
  const int n = lane & 15;
  const int nc = (n < 10) ? n : 9;       // clamp; junk cols masked in epilogue
  const int kh8 = (lane >> 5) * 8;

  // zero acts (pads rely on this; valid slots rewritten per group)
  for (int i = tid; i < 4*AS; i += 384) {
    ((unsigned*)a1h)[i] = 0u; ((unsigned*)a1l)[i] = 0u;
    ((unsigned*)a2h)[i] = 0u; ((unsigned*)a2l)[i] = 0u;
  }
  // stage w3-lo fragments into LDS (layout identical to ws image)
  {
    const f32x4* src = (const f32x4*)(wsr + OFF_W3L);
    f32x4* dst = (f32x4*)w3ls;
    for (int i = tid; i < 14336/4; i += 384) dst[i] = src[i];
  }

  // ---- per-role register state ----
  half8 w2h[20], w2l[20];      // c2 only (160 VGPR)
  half8 w3h[28];               // c3 only (112 VGPR)
  float w1c[12], sc1 = 0.f, sh1 = 0.f;
  int ot3 = 0, p3 = 0, lb3 = 0, idx3 = 0;

  if (isC2) {
    const int ot = wid;
    #pragma unroll
    for (int sk = 0; sk < 20; ++sk) {
      w2h[sk] = *(const half8*)(wsr + OFF_W2H + (size_t)((sk*2 + ot)*64 + lane)*4);
      w2l[sk] = *(const half8*)(wsr + OFF_W2L + (size_t)((sk*2 + ot)*64 + lane)*4);
    }
  } else {
    idx3 = wid - 2;
    ot3 = idx3 & 1;
    p3 = idx3 >> 1;
    lb3 = 2*p3 + ((lane >> 4) & 1);
    #pragma unroll
    for (int sk = 0; sk < 28; ++sk)
      w3h[sk] = *(const half8*)(wsr + OFF_W3H + (size_t)((sk*2 + ot3)*64 + lane)*4);
    #pragma unroll
    for (int i = 0; i < 12; ++i) w1c[i] = wsr[OFF_W1T + i*64 + lane];
    sc1 = wsr[OFF_SC1 + lane]; sh1 = wsr[OFF_SH1 + lane];
  }
  const int rq2 = 4*(lane >> 5) + wid*32;        // c2 row base (ot=wid)
  const int rq3 = 4*(lane >> 5) + ot3*32;        // c3 row base

  __syncthreads();

  // c2 conv2 for one pair of one group
  auto conv2_pair = [&](int abuf, int bbuf, int p, int g) {
    const int lb = 2*p + ((lane >> 4) & 1);
    const _Float16* bhp = &a1h[abuf][lb*AS];
    const _Float16* blp = &a1l[abuf][lb*AS];
    f32x16 acc;
    #pragma unroll
    for (int r = 0; r < 16; ++r) acc[r] = 0.f;
    #pragma unroll
    for (int sk = 0; sk < 20; ++sk) {
      const int tap = sk >> 2, icb = (sk & 3)*16;
      const int off = (nc + tap + 1)*72 + icb + kh8;
      const half8 bh = *(const half8*)(bhp + off);
      const half8 bl = *(const half8*)(blp + off);
      acc = mfma16(w2h[sk], bh, acc);
      acc = mfma16(w2h[sk], bl, acc);
      acc = mfma16(w2l[sk], bh, acc);
    }
    if (n < 10) {
      #pragma unroll
      for (int q = 0; q < 4; ++q) {
        const int rowb = 8*q + rq2;
        const f32x4 sc = *(const f32x4*)(wsr + OFF_SC2 + rowb);
        const f32x4 sh = *(const f32x4*)(wsr + OFF_SH2 + rowb);
        half4 h4, l4;
        #pragma unroll
        for (int r = 0; r < 4; ++r) {
          float v = sc[r]*acc[4*q + r] + sh[r];
          v = v > 0.f ? v : 0.f;
          _Float16 hi = (_Float16)v;
          h4[r] = hi;
          l4[r] = (_Float16)(v - (float)hi);
        }
        *(half4*)(&a2h[bbuf][lb*AS + (n + 3)*72 + rowb]) = h4;
        *(half4*)(&a2l[bbuf][lb*AS + (n + 3)*72 + rowb]) = l4;
      }
    }
  };

  for (int it = 0; it <= NGRP; ++it) {
    const int g = blockIdx.x*NGRP + it;
    const int cb = it & 1;       // buffers for group g
    // ---------------- Seg1 ----------------
    if (isC2) {
      if (it > 0) conv2_pair(cb ^ 1, cb ^ 1, 1, g - 1);
    } else {
      if (it < NGRP) {
        // conv1 for batch g*4 + idx3 (fp32 VALU, lane = out channel)
        const size_t bi = (size_t)g*4 + idx3;
        float xv[4][12];
        #pragma unroll
        for (int c = 0; c < 4; ++c) { xv[c][0] = 0.f; xv[c][11] = 0.f; }
        #pragma unroll
        for (int tt = 0; tt < 10; ++tt)
          #pragma unroll
          for (int c = 0; c < 4; ++c)
            xv[c][1 + tt] = x[bi*400 + (90 + tt)*4 + c];
        float a1[10];
        #pragma unroll
        for (int t = 0; t < 10; ++t) a1[t] = 0.f;
        #pragma unroll
        for (int c = 0; c < 4; ++c)
          #pragma unroll
          for (int k = 0; k < 3; ++k) {
            const float wv = w1c[c*3 + k];
            #pragma unroll
            for (int t = 0; t < 10; ++t) a1[t] += wv * xv[c][t + k];
          }
        #pragma unroll
        for (int t = 0; t < 10; ++t) {
          float v = sc1*a1[t] + sh1;
          v = v > 0.f ? v : 0.f;
          _Float16 hi = (_Float16)v;
          a1h[cb][idx3*AS + (3 + t)*72 + lane] = hi;
          a1l[cb][idx3*AS + (3 + t)*72 + lane] = (_Float16)(v - (float)hi);
        }
      }
    }
    __syncthreads();
    // ---------------- Seg2 ----------------
    if (isC2) {
      if (it < NGRP) conv2_pair(cb, cb, 0, g);
    } else {
      if (it > 0) {
        const int rb = cb ^ 1;   // act2 buffer of group g-1
        const _Float16* bhp = &a2h[rb][lb3*AS];
        const _Float16* blp = &a2l[rb][lb3*AS];
        f32x16 acc;
        #pragma unroll
        for (int r = 0; r < 16; ++r) acc[r] = 0.f;
        #pragma unroll
        for (int sk = 0; sk < 28; ++sk) {
          const int tap = sk >> 2, icb = (sk & 3)*16;
          const int off = (nc + tap)*72 + icb + kh8;
          const half8 bh = *(const half8*)(bhp + off);
          const half8 bl = *(const half8*)(blp + off);
          const half8 wl = *(const half8*)(w3ls + ((size_t)(sk*2 + ot3)*64 + lane)*8);
          acc = mfma16(w3h[sk], bh, acc);
          acc = mfma16(w3h[sk], bl, acc);
          acc = mfma16(wl, bh, acc);
        }
        #pragma unroll
        for (int q = 0; q < 4; ++q) {
          const int rowb = 8*q + rq3;
          const f32x4 sc = *(const f32x4*)(wsr + OFF_SC3 + rowb);
          const f32x4 sh = *(const f32x4*)(wsr + OFF_SH3 + rowb);
          f32x4 v;
          #pragma unroll
          for (int r = 0; r < 4; ++r) {
            float t = sc[r]*acc[4*q + r] + sh[r];
            t = t > 0.f ? t : 0.f;
            v[r] = (n < 10) ? t : 0.f;
          }
          #pragma unroll
          for (int r = 0; r < 4; ++r) {
            v[r] += __shfl_xor(v[r], 1, 16);
            v[r] += __shfl_xor(v[r], 2, 16);
            v[r] += __shfl_xor(v[r], 4, 16);
            v[r] += __shfl_xor(v[r], 8, 16);
          }
          if (n == 0)
            *(f32x4*)(sfp + ((size_t)(g - 1)*4 + lb3)*64 + rowb) = v * 0.1f;
        }
      }
    }
    __syncthreads();
  }
}

// ============================ RNN ============================
__global__ __launch_bounds__(256) void rnn_kernel(
    const float* __restrict__ x, const float* __restrict__ wsr,
    const float* __restrict__ A, float* __restrict__ hout)
{
  __shared__ float hbuf[16][20];   // padded rows; 16 groups per block
  int tid = blockIdx.x * 256 + threadIdx.x;
  int b = tid >> 4;
  int j = tid & 15;
  int g = threadIdx.x >> 4;

  float Arow[16];
  const float4* Ap = (const float4*)(A + j*16);
  #pragma unroll
  for (int q = 0; q < 4; ++q) { float4 v = Ap[q]; Arow[4*q]=v.x; Arow[4*q+1]=v.y; Arow[4*q+2]=v.z; Arow[4*q+3]=v.w; }
  float pb0 = wsr[OFF_PB + 0*16 + j];
  float pb1 = wsr[OFF_PB + 1*16 + j];
  float pb2 = wsr[OFF_PB + 2*16 + j];
  float pb3 = wsr[OFF_PB + 3*16 + j];
  float biasv = wsr[OFF_PBB + j];

  const float4* xb = (const float4*)(x + (size_t)b*400);
  float h = 0.f;
  float4 cur[5], nxt[5];
  #pragma unroll
  for (int q = 0; q < 5; ++q) cur[q] = xb[q];
  for (int tc = 0; tc < 100; tc += 5) {
    if (tc + 5 < 100) {
      #pragma unroll
      for (int q = 0; q < 5; ++q) nxt[q] = xb[tc+5+q];
    }
    #pragma unroll
    for (int q = 0; q < 5; ++q) {
      float4 cx = cur[q];
      float u = biasv + cx.x*pb0 + cx.y*pb1 + cx.z*pb2 + cx.w*pb3;
      hbuf[g][j] = h;                       // same-wave LDS broadcast
      const f32x4* hp = (const f32x4*)hbuf[g];
      #pragma unroll
      for (int qq = 0; qq < 4; ++qq) {
        f32x4 hv = hp[qq];
        u += hv[0]*Arow[4*qq] + hv[1]*Arow[4*qq+1] + hv[2]*Arow[4*qq+2] + hv[3]*Arow[4*qq+3];
      }
      float e = __expf(2.f*u);
      h = 1.f - 2.f/(e + 1.f);
    }
    #pragma unroll
    for (int q = 0; q < 5; ++q) cur[q] = nxt[q];
  }
  hout[(size_t)b*16 + j] = h;
}

// ============================ tail ============================
// lane = (b4 = lane>>4, og = lane&15): 4 batches/wave, o-quad per lane.
// All stage buffers are wave-private per (wid) -> no in-loop barriers.
__global__ __launch_bounds__(256) void tail_kernel(
    const float* __restrict__ wsr,
    const float* __restrict__ g1_w, const float* __restrict__ g1_b,
    const float* __restrict__ g2_w, const float* __restrict__ g2_b,
    const float* __restrict__ h1_w, const float* __restrict__ h1_b,
    const float* __restrict__ h2_w, const float* __restrict__ h2_b,
    const float* __restrict__ out_b, float* __restrict__ out)
{
  __shared__ float sG1[128*64];   // 32 KB, [k][o]
  __shared__ float sG2[64*64];    // 16 KB
  __shared__ float sH1[64*32];    // 8 KB
  __shared__ float sH2[32*3];
  __shared__ float sCO[16*64];    // 4 KB
  __shared__ float wbuf[16][132];
  __shared__ float tbuf[16][68];
  __shared__ float t2buf[16][36];
  __shared__ float hbuf[4][64];
  int tid = threadIdx.x;
  for (int i = tid; i < 128*64; i += 256) sG1[i] = g1_w[i];
  for (int i = tid; i < 64*64; i += 256) sG2[i] = g2_w[i];
  for (int i = tid; i < 64*32; i += 256) sH1[i] = h1_w[i];
  for (int i = tid; i < 96; i += 256) sH2[i] = h2_w[i];
  for (int i = tid; i < 16*64; i += 256) sCO[i] = wsr[OFF_CO + i];
  __syncthreads();

  const int lane = tid & 63, wid = tid >> 6;
  const int b4 = lane >> 4, og = lane & 15;
  const int wb = wid*4 + b4;
  const float* sf = wsr + OFF_SF;
  const float* hws = wsr + OFF_H;
  const f32x4 g1b4 = *(const f32x4*)(g1_b + 4*og);
  const f32x4 g2b4 = *(const f32x4*)(g2_b + 4*og);
  const f32x4 ob4  = *(const f32x4*)(out_b + 4*og);
  const f32x2 h1b2 = *(const f32x2*)(h1_b + 2*og);
  const float h2bv = (og < 3) ? h2_b[og] : 0.f;

  for (int seg = 0; seg < 4; ++seg) {
    const int wq = blockIdx.x*64 + seg*16 + wid*4;
    const int batch = wq + b4;
    hbuf[wid][lane] = hws[(size_t)wq*16 + lane];
    const f32x4 sfv = *(const f32x4*)(sf + (size_t)batch*64 + 4*og);
    f32x4 lcv = ob4;
    #pragma unroll
    for (int j = 0; j < 16; ++j) {
      const float hj = hbuf[wid][b4*16 + j];
      const f32x4 co = *(const f32x4*)(sCO + j*64 + 4*og);
      lcv += hj * co;
    }
    *(f32x4*)(&wbuf[wb][4*og]) = sfv;
    *(f32x4*)(&wbuf[wb][64 + 4*og]) = lcv;
    // L1: combined(128) @ g1 -> tanh
    f32x4 u = g1b4;
    #pragma unroll 8
    for (int k = 0; k < 128; ++k)
      u += wbuf[wb][k] * *(const f32x4*)(sG1 + k*64 + 4*og);
    f32x4 t1;
    #pragma unroll
    for (int r = 0; r < 4; ++r) {
      float e = __expf(2.f*u[r]);
      t1[r] = 1.f - 2.f/(e + 1.f);
    }
    *(f32x4*)(&tbuf[wb][4*og]) = t1;
    // L2: t1(64) @ g2 -> sigmoid -> gate
    f32x4 u2 = g2b4;
    #pragma unroll 8
    for (int k = 0; k < 64; ++k)
      u2 += tbuf[wb][k] * *(const f32x4*)(sG2 + k*64 + 4*og);
    f32x4 filt;
    #pragma unroll
    for (int r = 0; r < 4; ++r)
      filt[r] = sfv[r] / (1.f + __expf(-u2[r]));
    *(f32x4*)(&wbuf[wb][4*og]) = filt;
    // L3: filt(64) @ h1 -> relu (32 outs: 2 per lane)
    f32x2 r2 = h1b2;
    #pragma unroll 8
    for (int k = 0; k < 64; ++k)
      r2 += wbuf[wb][k] * *(const f32x2*)(sH1 + k*32 + 2*og);
    r2[0] = fmaxf(r2[0], 0.f); r2[1] = fmaxf(r2[1], 0.f);
    *(f32x2*)(&t2buf[wb][2*og]) = r2;
    // L4: (32) @ h2 -> 3 logits
    if (og < 3) {
      float a = h2bv;
      #pragma unroll
      for (int k = 0; k < 32; ++k) a += t2buf[wb][k] * sH2[k*3 + og];
      out[(size_t)batch*3 + og] = a;
    }
  }
}

// ============================ launch ============================
extern "C" void kernel_launch(void* const* d_in, const int* in_sizes, int n_in,
                              void* d_out, int out_size, void* d_ws, size_t ws_size,
                              hipStream_t stream) {
  const float* x       = (const float*)d_in[0];
  const float* conv1_w = (const float*)d_in[1];
  const float* conv1_b = (const float*)d_in[2];
  const float* conv2_w = (const float*)d_in[3];
  const float* conv2_b = (const float*)d_in[4];
  const float* conv3_w = (const float*)d_in[5];
  const float* conv3_b = (const float*)d_in[6];
  const float* bn1_g   = (const float*)d_in[7];
  const float* bn1_b   = (const float*)d_in[8];
  const float* bn2_g   = (const float*)d_in[9];
  const float* bn2_b   = (const float*)d_in[10];
  const float* bn3_g   = (const float*)d_in[11];
  const float* bn3_b   = (const float*)d_in[12];
  const float* proj_w  = (const float*)d_in[13];
  const float* proj_b  = (const float*)d_in[14];
  const float* A       = (const float*)d_in[15];
  const float* Bm      = (const float*)d_in[16];
  const float* Cm      = (const float*)d_in[17];
  const float* out_w   = (const float*)d_in[18];
  const float* out_b   = (const float*)d_in[19];
  const float* g1_w    = (const float*)d_in[20];
  const float* g1_b    = (const float*)d_in[21];
  const float* g2_w    = (const float*)d_in[22];
  const float* g2_b    = (const float*)d_in[23];
  const float* h1_w    = (const float*)d_in[24];
  const float* h1_b    = (const float*)d_in[25];
  const float* h2_w    = (const float*)d_in[26];
  const float* h2_b    = (const float*)d_in[27];
  float* ws = (float*)d_ws;
  float* out = (float*)d_out;

  prep_kernel<<<64, 256, 0, stream>>>(conv1_w, conv1_b, conv2_w, conv2_b,
      conv3_w, conv3_b, bn1_g, bn1_b, bn2_g, bn2_b, bn3_g, bn3_b,
      proj_w, proj_b, A, Bm, Cm, out_w, ws);
  conv_kernel<<<NB/(4*NGRP), 384, 0, stream>>>(x, ws, ws + OFF_SF);
  rnn_kernel<<<NB*16/256, 256, 0, stream>>>(x, ws, A, ws + OFF_H);
  tail_kernel<<<NB/64, 256, 0, stream>>>(ws, g1_w, g1_b, g2_w, g2_b,
      h1_w, h1_b, h2_w, h2_b, out_b, out);
}

// Round 5
// 516.557 us; speedup vs baseline: 1.0011x; 1.0011x over previous
//
#include <hip/hip_runtime.h>
#include <cstddef>

#define NB 16384
#define NGRP 16
#define AS 1160   // act batch stride in halves (16*72 + 8 pad)

typedef __attribute__((ext_vector_type(8))) _Float16 half8;
typedef __attribute__((ext_vector_type(4))) _Float16 half4;
typedef __attribute__((ext_vector_type(4))) float f32x4;
typedef __attribute__((ext_vector_type(2))) float f32x2;
typedef __attribute__((ext_vector_type(16))) float f32x16;

// ---- ws float offsets ----
#define OFF_W1T 0                      // 12*64
#define OFF_SC1 768
#define OFF_SH1 832
#define OFF_SC2 896
#define OFF_SH2 960
#define OFF_SC3 1024
#define OFF_SH3 1088
#define OFF_PB  1152                   // 4*16
#define OFF_PBB 1216                   // 16
#define OFF_CO  1232                   // 16*64 -> 2256
#define OFF_W2H 2304                   // 20*2*64*8 halves = 10240 floats
#define OFF_W2L 12544                  // 10240 floats
#define OFF_W3H 22784                  // 28*2*64*8 halves = 14336 floats
#define OFF_W3L 37120                  // 14336 floats
#define OFF_SF  51456                  // NB*64
#define OFF_H   (51456 + NB*64)        // NB*16

static __device__ __forceinline__ f32x16 mfma16(half8 a, half8 b, f32x16 c) {
  return __builtin_amdgcn_mfma_f32_32x32x16_f16(a, b, c, 0, 0, 0);
}

// ============================ prep ============================
__global__ __launch_bounds__(256) void prep_kernel(
    const float* __restrict__ conv1_w, const float* __restrict__ conv1_b,
    const float* __restrict__ conv2_w, const float* __restrict__ conv2_b,
    const float* __restrict__ conv3_w, const float* __restrict__ conv3_b,
    const float* __restrict__ bn1_g, const float* __restrict__ bn1_b,
    const float* __restrict__ bn2_g, const float* __restrict__ bn2_b,
    const float* __restrict__ bn3_g, const float* __restrict__ bn3_b,
    const float* __restrict__ proj_w, const float* __restrict__ proj_b,
    const float* __restrict__ A, const float* __restrict__ Bm,
    const float* __restrict__ Cm, const float* __restrict__ out_w,
    float* __restrict__ ws)
{
  int tid = blockIdx.x * blockDim.x + threadIdx.x;
  int nt = gridDim.x * blockDim.x;
  const float s = rsqrtf(1.0f + 1e-5f);

  for (int i = tid; i < 64*12; i += nt) {       // w1t[(c*3+k)*64+o]
    int o = i & 63, rk = i >> 6;
    ws[OFF_W1T + i] = conv1_w[o*12 + rk];
  }
  for (int o = tid; o < 64; o += nt) {
    float s1 = bn1_g[o]*s, s2 = bn2_g[o]*s, s3 = bn3_g[o]*s;
    ws[OFF_SC1+o] = s1; ws[OFF_SH1+o] = s1*conv1_b[o] + bn1_b[o];
    ws[OFF_SC2+o] = s2; ws[OFF_SH2+o] = s2*conv2_b[o] + bn2_b[o];
    ws[OFF_SC3+o] = s3; ws[OFF_SH3+o] = s3*conv3_b[o] + bn3_b[o];
  }
  // conv2 A-fragments for 32x32x16, k = tap*64 + ic (tap-major), hi/lo split.
  {
    _Float16* w2h = (_Float16*)(ws + OFF_W2H);
    _Float16* w2l = (_Float16*)(ws + OFF_W2L);
    for (int i = tid; i < 20*2*64; i += nt) {
      int lane = i & 63, ot = (i >> 6) & 1, sk = i >> 7;
      int tap = sk >> 2, ic0 = (sk & 3)*16 + (lane >> 5)*8;
      int o = ot*32 + (lane & 31);
      #pragma unroll
      for (int j = 0; j < 8; ++j) {
        float w = conv2_w[o*320 + (ic0 + j)*5 + tap];
        _Float16 hi = (_Float16)w;
        w2h[(size_t)i*8 + j] = hi;
        w2l[(size_t)i*8 + j] = (_Float16)(w - (float)hi);
      }
    }
  }
  {
    _Float16* w3h = (_Float16*)(ws + OFF_W3H);
    _Float16* w3l = (_Float16*)(ws + OFF_W3L);
    for (int i = tid; i < 28*2*64; i += nt) {
      int lane = i & 63, ot = (i >> 6) & 1, sk = i >> 7;
      int tap = sk >> 2, ic0 = (sk & 3)*16 + (lane >> 5)*8;
      int o = ot*32 + (lane & 31);
      #pragma unroll
      for (int j = 0; j < 8; ++j) {
        float w = conv3_w[o*448 + (ic0 + j)*7 + tap];
        _Float16 hi = (_Float16)w;
        w3h[(size_t)i*8 + j] = hi;
        w3l[(size_t)i*8 + j] = (_Float16)(w - (float)hi);
      }
    }
  }
  // PB[c][j] = sum_m proj_w[c][m]*Bm[m][j]
  for (int i = tid; i < 64; i += nt) {
    int c = i >> 4, j = i & 15;
    float acc = 0.f;
    for (int m = 0; m < 64; ++m) acc += proj_w[c*64+m]*Bm[m*16+j];
    ws[OFF_PB + i] = acc;
  }
  for (int j = tid; j < 16; j += nt) {
    float acc = 0.f;
    for (int m = 0; m < 64; ++m) acc += proj_b[m]*Bm[m*16+j];
    ws[OFF_PBB + j] = acc;
  }
  // CO[j][o] = sum_m Cm[j][m]*out_w[m][o]
  for (int i = tid; i < 16*64; i += nt) {
    int j = i >> 6, o = i & 63;
    float acc = 0.f;
    for (int m = 0; m < 64; ++m) acc += Cm[j*64+m]*out_w[m*64+o];
    ws[OFF_CO + i] = acc;
  }
}

// ============================ conv stack ============================
// Roles: waves 0-1 = c2 (w2 hi+lo in regs, ot=wid, 2 pairs);
//        waves 2-5 = c3 (w3 hi in regs, lo from LDS; (ot,pair) split; +conv1).
// Pipeline per iter: Seg1: c3 conv1(g), c2 conv2-pair1(g-1);
//                    Seg2: c2 conv2-pair0(g), c3 conv3(g-1) -> sf.
// NOTE: no min-waves/EU in launch_bounds — (384,2) capped arch VGPRs at 128
// and spilled ~90 regs/wave to scratch (399+133 MB HBM traffic, r3/r4 counters).
__global__ __launch_bounds__(384) void conv_kernel(
    const float* __restrict__ x, const float* __restrict__ wsr,
    float* __restrict__ sfp)
{
  __shared__ __align__(16) _Float16 a1h[2][4*AS];
  __shared__ __align__(16) _Float16 a1l[2][4*AS];
  __shared__ __align__(16) _Float16 a2h[2][4*AS];
  __shared__ __align__(16) _Float16 a2l[2][4*AS];
  __shared__ __align__(16) _Float16 w3ls[28*2*64*8];   // 57344 B

  const int tid = threadIdx.x;
  const int lane = tid & 63;
  const int wid = tid >> 6;
  const bool isC2 = (wid < 2);
  const int n = lane & 15;
  const int nc = (n < 10) ? n : 9;       // clamp; junk cols masked in epilogue
  const int kh8 = (lane >> 5) * 8;

  // zero acts (pads rely on this; valid slots rewritten per group)
  for (int i = tid; i < 4*AS; i += 384) {
    ((unsigned*)a1h)[i] = 0u; ((unsigned*)a1l)[i] = 0u;
    ((unsigned*)a2h)[i] = 0u; ((unsigned*)a2l)[i] = 0u;
  }
  // stage w3-lo fragments into LDS (layout identical to ws image)
  {
    const f32x4* src = (const f32x4*)(wsr + OFF_W3L);
    f32x4* dst = (f32x4*)w3ls;
    for (int i = tid; i < 14336/4; i += 384) dst[i] = src[i];
  }

  // ---- per-role register state ----
  half8 w2h[20], w2l[20];      // c2 only (160 VGPR)
  half8 w3h[28];               // c3 only (112 VGPR)
  float w1c[12], sc1 = 0.f, sh1 = 0.f;
  int ot3 = 0, p3 = 0, lb3 = 0, idx3 = 0;

  if (isC2) {
    const int ot = wid;
    #pragma unroll
    for (int sk = 0; sk < 20; ++sk) {
      w2h[sk] = *(const half8*)(wsr + OFF_W2H + (size_t)((sk*2 + ot)*64 + lane)*4);
      w2l[sk] = *(const half8*)(wsr + OFF_W2L + (size_t)((sk*2 + ot)*64 + lane)*4);
    }
  } else {
    idx3 = wid - 2;
    ot3 = idx3 & 1;
    p3 = idx3 >> 1;
    lb3 = 2*p3 + ((lane >> 4) & 1);
    #pragma unroll
    for (int sk = 0; sk < 28; ++sk)
      w3h[sk] = *(const half8*)(wsr + OFF_W3H + (size_t)((sk*2 + ot3)*64 + lane)*4);
    #pragma unroll
    for (int i = 0; i < 12; ++i) w1c[i] = wsr[OFF_W1T + i*64 + lane];
    sc1 = wsr[OFF_SC1 + lane]; sh1 = wsr[OFF_SH1 + lane];
  }
  const int rq2 = 4*(lane >> 5) + wid*32;        // c2 row base (ot=wid)
  const int rq3 = 4*(lane >> 5) + ot3*32;        // c3 row base

  __syncthreads();

  // c2 conv2 for one pair of one group
  auto conv2_pair = [&](int abuf, int bbuf, int p, int g) {
    const int lb = 2*p + ((lane >> 4) & 1);
    const _Float16* bhp = &a1h[abuf][lb*AS];
    const _Float16* blp = &a1l[abuf][lb*AS];
    f32x16 acc;
    #pragma unroll
    for (int r = 0; r < 16; ++r) acc[r] = 0.f;
    #pragma unroll
    for (int sk = 0; sk < 20; ++sk) {
      const int tap = sk >> 2, icb = (sk & 3)*16;
      const int off = (nc + tap + 1)*72 + icb + kh8;
      const half8 bh = *(const half8*)(bhp + off);
      const half8 bl = *(const half8*)(blp + off);
      acc = mfma16(w2h[sk], bh, acc);
      acc = mfma16(w2h[sk], bl, acc);
      acc = mfma16(w2l[sk], bh, acc);
    }
    if (n < 10) {
      #pragma unroll
      for (int q = 0; q < 4; ++q) {
        const int rowb = 8*q + rq2;
        const f32x4 sc = *(const f32x4*)(wsr + OFF_SC2 + rowb);
        const f32x4 sh = *(const f32x4*)(wsr + OFF_SH2 + rowb);
        half4 h4, l4;
        #pragma unroll
        for (int r = 0; r < 4; ++r) {
          float v = sc[r]*acc[4*q + r] + sh[r];
          v = v > 0.f ? v : 0.f;
          _Float16 hi = (_Float16)v;
          h4[r] = hi;
          l4[r] = (_Float16)(v - (float)hi);
        }
        *(half4*)(&a2h[bbuf][lb*AS + (n + 3)*72 + rowb]) = h4;
        *(half4*)(&a2l[bbuf][lb*AS + (n + 3)*72 + rowb]) = l4;
      }
    }
  };

  for (int it = 0; it <= NGRP; ++it) {
    const int g = blockIdx.x*NGRP + it;
    const int cb = it & 1;       // buffers for group g
    // ---------------- Seg1 ----------------
    if (isC2) {
      if (it > 0) conv2_pair(cb ^ 1, cb ^ 1, 1, g - 1);
    } else {
      if (it < NGRP) {
        // conv1 for batch g*4 + idx3 (fp32 VALU, lane = out channel)
        const size_t bi = (size_t)g*4 + idx3;
        float xv[4][12];
        #pragma unroll
        for (int c = 0; c < 4; ++c) { xv[c][0] = 0.f; xv[c][11] = 0.f; }
        #pragma unroll
        for (int tt = 0; tt < 10; ++tt)
          #pragma unroll
          for (int c = 0; c < 4; ++c)
            xv[c][1 + tt] = x[bi*400 + (90 + tt)*4 + c];
        float a1[10];
        #pragma unroll
        for (int t = 0; t < 10; ++t) a1[t] = 0.f;
        #pragma unroll
        for (int c = 0; c < 4; ++c)
          #pragma unroll
          for (int k = 0; k < 3; ++k) {
            const float wv = w1c[c*3 + k];
            #pragma unroll
            for (int t = 0; t < 10; ++t) a1[t] += wv * xv[c][t + k];
          }
        #pragma unroll
        for (int t = 0; t < 10; ++t) {
          float v = sc1*a1[t] + sh1;
          v = v > 0.f ? v : 0.f;
          _Float16 hi = (_Float16)v;
          a1h[cb][idx3*AS + (3 + t)*72 + lane] = hi;
          a1l[cb][idx3*AS + (3 + t)*72 + lane] = (_Float16)(v - (float)hi);
        }
      }
    }
    __syncthreads();
    // ---------------- Seg2 ----------------
    if (isC2) {
      if (it < NGRP) conv2_pair(cb, cb, 0, g);
    } else {
      if (it > 0) {
        const int rb = cb ^ 1;   // act2 buffer of group g-1
        const _Float16* bhp = &a2h[rb][lb3*AS];
        const _Float16* blp = &a2l[rb][lb3*AS];
        f32x16 acc;
        #pragma unroll
        for (int r = 0; r < 16; ++r) acc[r] = 0.f;
        #pragma unroll
        for (int sk = 0; sk < 28; ++sk) {
          const int tap = sk >> 2, icb = (sk & 3)*16;
          const int off = (nc + tap)*72 + icb + kh8;
          const half8 bh = *(const half8*)(bhp + off);
          const half8 bl = *(const half8*)(blp + off);
          const half8 wl = *(const half8*)(w3ls + ((size_t)(sk*2 + ot3)*64 + lane)*8);
          acc = mfma16(w3h[sk], bh, acc);
          acc = mfma16(w3h[sk], bl, acc);
          acc = mfma16(wl, bh, acc);
        }
        #pragma unroll
        for (int q = 0; q < 4; ++q) {
          const int rowb = 8*q + rq3;
          const f32x4 sc = *(const f32x4*)(wsr + OFF_SC3 + rowb);
          const f32x4 sh = *(const f32x4*)(wsr + OFF_SH3 + rowb);
          f32x4 v;
          #pragma unroll
          for (int r = 0; r < 4; ++r) {
            float t = sc[r]*acc[4*q + r] + sh[r];
            t = t > 0.f ? t : 0.f;
            v[r] = (n < 10) ? t : 0.f;
          }
          #pragma unroll
          for (int r = 0; r < 4; ++r) {
            v[r] += __shfl_xor(v[r], 1, 16);
            v[r] += __shfl_xor(v[r], 2, 16);
            v[r] += __shfl_xor(v[r], 4, 16);
            v[r] += __shfl_xor(v[r], 8, 16);
          }
          if (n == 0)
            *(f32x4*)(sfp + ((size_t)(g - 1)*4 + lb3)*64 + rowb) = v * 0.1f;
        }
      }
    }
    __syncthreads();
  }
}

// ============================ RNN ============================
__global__ __launch_bounds__(256) void rnn_kernel(
    const float* __restrict__ x, const float* __restrict__ wsr,
    const float* __restrict__ A, float* __restrict__ hout)
{
  __shared__ float hbuf[16][20];   // padded rows; 16 groups per block
  int tid = blockIdx.x * 256 + threadIdx.x;
  int b = tid >> 4;
  int j = tid & 15;
  int g = threadIdx.x >> 4;

  float Arow[16];
  const float4* Ap = (const float4*)(A + j*16);
  #pragma unroll
  for (int q = 0; q < 4; ++q) { float4 v = Ap[q]; Arow[4*q]=v.x; Arow[4*q+1]=v.y; Arow[4*q+2]=v.z; Arow[4*q+3]=v.w; }
  float pb0 = wsr[OFF_PB + 0*16 + j];
  float pb1 = wsr[OFF_PB + 1*16 + j];
  float pb2 = wsr[OFF_PB + 2*16 + j];
  float pb3 = wsr[OFF_PB + 3*16 + j];
  float biasv = wsr[OFF_PBB + j];

  const float4* xb = (const float4*)(x + (size_t)b*400);
  float h = 0.f;
  float4 cur[5], nxt[5];
  #pragma unroll
  for (int q = 0; q < 5; ++q) cur[q] = xb[q];
  for (int tc = 0; tc < 100; tc += 5) {
    if (tc + 5 < 100) {
      #pragma unroll
      for (int q = 0; q < 5; ++q) nxt[q] = xb[tc+5+q];
    }
    #pragma unroll
    for (int q = 0; q < 5; ++q) {
      float4 cx = cur[q];
      float u = biasv + cx.x*pb0 + cx.y*pb1 + cx.z*pb2 + cx.w*pb3;
      hbuf[g][j] = h;                       // same-wave LDS broadcast
      const f32x4* hp = (const f32x4*)hbuf[g];
      #pragma unroll
      for (int qq = 0; qq < 4; ++qq) {
        f32x4 hv = hp[qq];
        u += hv[0]*Arow[4*qq] + hv[1]*Arow[4*qq+1] + hv[2]*Arow[4*qq+2] + hv[3]*Arow[4*qq+3];
      }
      float e = __expf(2.f*u);
      h = 1.f - 2.f/(e + 1.f);
    }
    #pragma unroll
    for (int q = 0; q < 5; ++q) cur[q] = nxt[q];
  }
  hout[(size_t)b*16 + j] = h;
}

// ============================ tail ============================
// lane = (b4 = lane>>4, og = lane&15): 4 batches/wave, o-quad per lane.
// All stage buffers are wave-private per (wid) -> no in-loop barriers.
__global__ __launch_bounds__(256) void tail_kernel(
    const float* __restrict__ wsr,
    const float* __restrict__ g1_w, const float* __restrict__ g1_b,
    const float* __restrict__ g2_w, const float* __restrict__ g2_b,
    const float* __restrict__ h1_w, const float* __restrict__ h1_b,
    const float* __restrict__ h2_w, const float* __restrict__ h2_b,
    const float* __restrict__ out_b, float* __restrict__ out)
{
  __shared__ float sG1[128*64];   // 32 KB, [k][o]
  __shared__ float sG2[64*64];    // 16 KB
  __shared__ float sH1[64*32];    // 8 KB
  __shared__ float sH2[32*3];
  __shared__ float sCO[16*64];    // 4 KB
  __shared__ float wbuf[16][132];
  __shared__ float tbuf[16][68];
  __shared__ float t2buf[16][36];
  __shared__ float hbuf[4][64];
  int tid = threadIdx.x;
  for (int i = tid; i < 128*64; i += 256) sG1[i] = g1_w[i];
  for (int i = tid; i < 64*64; i += 256) sG2[i] = g2_w[i];
  for (int i = tid; i < 64*32; i += 256) sH1[i] = h1_w[i];
  for (int i = tid; i < 96; i += 256) sH2[i] = h2_w[i];
  for (int i = tid; i < 16*64; i += 256) sCO[i] = wsr[OFF_CO + i];
  __syncthreads();

  const int lane = tid & 63, wid = tid >> 6;
  const int b4 = lane >> 4, og = lane & 15;
  const int wb = wid*4 + b4;
  const float* sf = wsr + OFF_SF;
  const float* hws = wsr + OFF_H;
  const f32x4 g1b4 = *(const f32x4*)(g1_b + 4*og);
  const f32x4 g2b4 = *(const f32x4*)(g2_b + 4*og);
  const f32x4 ob4  = *(const f32x4*)(out_b + 4*og);
  const f32x2 h1b2 = *(const f32x2*)(h1_b + 2*og);
  const float h2bv = (og < 3) ? h2_b[og] : 0.f;

  for (int seg = 0; seg < 4; ++seg) {
    const int wq = blockIdx.x*64 + seg*16 + wid*4;
    const int batch = wq + b4;
    hbuf[wid][lane] = hws[(size_t)wq*16 + lane];
    const f32x4 sfv = *(const f32x4*)(sf + (size_t)batch*64 + 4*og);
    f32x4 lcv = ob4;
    #pragma unroll
    for (int j = 0; j < 16; ++j) {
      const float hj = hbuf[wid][b4*16 + j];
      const f32x4 co = *(const f32x4*)(sCO + j*64 + 4*og);
      lcv += hj * co;
    }
    *(f32x4*)(&wbuf[wb][4*og]) = sfv;
    *(f32x4*)(&wbuf[wb][64 + 4*og]) = lcv;
    // L1: combined(128) @ g1 -> tanh
    f32x4 u = g1b4;
    #pragma unroll 8
    for (int k = 0; k < 128; ++k)
      u += wbuf[wb][k] * *(const f32x4*)(sG1 + k*64 + 4*og);
    f32x4 t1;
    #pragma unroll
    for (int r = 0; r < 4; ++r) {
      float e = __expf(2.f*u[r]);
      t1[r] = 1.f - 2.f/(e + 1.f);
    }
    *(f32x4*)(&tbuf[wb][4*og]) = t1;
    // L2: t1(64) @ g2 -> sigmoid -> gate
    f32x4 u2 = g2b4;
    #pragma unroll 8
    for (int k = 0; k < 64; ++k)
      u2 += tbuf[wb][k] * *(const f32x4*)(sG2 + k*64 + 4*og);
    f32x4 filt;
    #pragma unroll
    for (int r = 0; r < 4; ++r)
      filt[r] = sfv[r] / (1.f + __expf(-u2[r]));
    *(f32x4*)(&wbuf[wb][4*og]) = filt;
    // L3: filt(64) @ h1 -> relu (32 outs: 2 per lane)
    f32x2 r2 = h1b2;
    #pragma unroll 8
    for (int k = 0; k < 64; ++k)
      r2 += wbuf[wb][k] * *(const f32x2*)(sH1 + k*32 + 2*og);
    r2[0] = fmaxf(r2[0], 0.f); r2[1] = fmaxf(r2[1], 0.f);
    *(f32x2*)(&t2buf[wb][2*og]) = r2;
    // L4: (32) @ h2 -> 3 logits
    if (og < 3) {
      float a = h2bv;
      #pragma unroll
      for (int k = 0; k < 32; ++k) a += t2buf[wb][k] * sH2[k*3 + og];
      out[(size_t)batch*3 + og] = a;
    }
  }
}

// ============================ launch ============================
extern "C" void kernel_launch(void* const* d_in, const int* in_sizes, int n_in,
                              void* d_out, int out_size, void* d_ws, size_t ws_size,
                              hipStream_t stream) {
  const float* x       = (const float*)d_in[0];
  const float* conv1_w = (const float*)d_in[1];
  const float* conv1_b = (const float*)d_in[2];
  const float* conv2_w = (const float*)d_in[3];
  const float* conv2_b = (const float*)d_in[4];
  const float* conv3_w = (const float*)d_in[5];
  const float* conv3_b = (const float*)d_in[6];
  const float* bn1_g   = (const float*)d_in[7];
  const float* bn1_b   = (const float*)d_in[8];
  const float* bn2_g   = (const float*)d_in[9];
  const float* bn2_b   = (const float*)d_in[10];
  const float* bn3_g   = (const float*)d_in[11];
  const float* bn3_b   = (const float*)d_in[12];
  const float* proj_w  = (const float*)d_in[13];
  const float* proj_b  = (const float*)d_in[14];
  const float* A       = (const float*)d_in[15];
  const float* Bm      = (const float*)d_in[16];
  const float* Cm      = (const float*)d_in[17];
  const float* out_w   = (const float*)d_in[18];
  const float* out_b   = (const float*)d_in[19];
  const float* g1_w    = (const float*)d_in[20];
  const float* g1_b    = (const float*)d_in[21];
  const float* g2_w    = (const float*)d_in[22];
  const float* g2_b    = (const float*)d_in[23];
  const float* h1_w    = (const float*)d_in[24];
  const float* h1_b    = (const float*)d_in[25];
  const float* h2_w    = (const float*)d_in[26];
  const float* h2_b    = (const float*)d_in[27];
  float* ws = (float*)d_ws;
  float* out = (float*)d_out;

  prep_kernel<<<64, 256, 0, stream>>>(conv1_w, conv1_b, conv2_w, conv2_b,
      conv3_w, conv3_b, bn1_g, bn1_b, bn2_g, bn2_b, bn3_g, bn3_b,
      proj_w, proj_b, A, Bm, Cm, out_w, ws);
  conv_kernel<<<NB/(4*NGRP), 384, 0, stream>>>(x, ws, ws + OFF_SF);
  rnn_kernel<<<NB*16/256, 256, 0, stream>>>(x, ws, A, ws + OFF_H);
  tail_kernel<<<NB/64, 256, 0, stream>>>(ws, g1_w, g1_b, g2_w, g2_b,
      h1_w, h1_b, h2_w, h2_b, out_b, out);
}

// Round 6
// 350.750 us; speedup vs baseline: 1.4743x; 1.4727x over previous
//
#include <hip/hip_runtime.h>
#include <cstddef>

#define NB 16384
#define NGRP 16
#define AS 1160   // act batch stride in halves (16*72 + 8 pad)

typedef __attribute__((ext_vector_type(8))) _Float16 half8;
typedef __attribute__((ext_vector_type(4))) _Float16 half4;
typedef __attribute__((ext_vector_type(4))) float f32x4;
typedef __attribute__((ext_vector_type(2))) float f32x2;
typedef __attribute__((ext_vector_type(16))) float f32x16;

// ---- ws float offsets ----
#define OFF_W1T 0                      // 12*64
#define OFF_SC1 768
#define OFF_SH1 832
#define OFF_SC2 896
#define OFF_SH2 960
#define OFF_SC3 1024
#define OFF_SH3 1088
#define OFF_PB  1152                   // 4*16
#define OFF_PBB 1216                   // 16
#define OFF_CO  1232                   // 16*64 -> 2256
#define OFF_W2H 2304                   // 20*2*64*8 halves = 10240 floats
#define OFF_W2L 12544                  // 10240 floats
#define OFF_W3H 22784                  // 28*2*64*8 halves = 14336 floats
#define OFF_W3L 37120                  // 14336 floats
#define OFF_SF  51456                  // NB*64
#define OFF_H   (51456 + NB*64)        // NB*16

static __device__ __forceinline__ f32x16 mfma16(half8 a, half8 b, f32x16 c) {
  return __builtin_amdgcn_mfma_f32_32x32x16_f16(a, b, c, 0, 0, 0);
}

// ============================ prep ============================
__global__ __launch_bounds__(256) void prep_kernel(
    const float* __restrict__ conv1_w, const float* __restrict__ conv1_b,
    const float* __restrict__ conv2_w, const float* __restrict__ conv2_b,
    const float* __restrict__ conv3_w, const float* __restrict__ conv3_b,
    const float* __restrict__ bn1_g, const float* __restrict__ bn1_b,
    const float* __restrict__ bn2_g, const float* __restrict__ bn2_b,
    const float* __restrict__ bn3_g, const float* __restrict__ bn3_b,
    const float* __restrict__ proj_w, const float* __restrict__ proj_b,
    const float* __restrict__ A, const float* __restrict__ Bm,
    const float* __restrict__ Cm, const float* __restrict__ out_w,
    float* __restrict__ ws)
{
  int tid = blockIdx.x * blockDim.x + threadIdx.x;
  int nt = gridDim.x * blockDim.x;
  const float s = rsqrtf(1.0f + 1e-5f);

  for (int i = tid; i < 64*12; i += nt) {       // w1t[(c*3+k)*64+o]
    int o = i & 63, rk = i >> 6;
    ws[OFF_W1T + i] = conv1_w[o*12 + rk];
  }
  for (int o = tid; o < 64; o += nt) {
    float s1 = bn1_g[o]*s, s2 = bn2_g[o]*s, s3 = bn3_g[o]*s;
    ws[OFF_SC1+o] = s1; ws[OFF_SH1+o] = s1*conv1_b[o] + bn1_b[o];
    ws[OFF_SC2+o] = s2; ws[OFF_SH2+o] = s2*conv2_b[o] + bn2_b[o];
    ws[OFF_SC3+o] = s3; ws[OFF_SH3+o] = s3*conv3_b[o] + bn3_b[o];
  }
  // conv2 A-fragments for 32x32x16, k = tap*64 + ic (tap-major), hi/lo split.
  {
    _Float16* w2h = (_Float16*)(ws + OFF_W2H);
    _Float16* w2l = (_Float16*)(ws + OFF_W2L);
    for (int i = tid; i < 20*2*64; i += nt) {
      int lane = i & 63, ot = (i >> 6) & 1, sk = i >> 7;
      int tap = sk >> 2, ic0 = (sk & 3)*16 + (lane >> 5)*8;
      int o = ot*32 + (lane & 31);
      #pragma unroll
      for (int j = 0; j < 8; ++j) {
        float w = conv2_w[o*320 + (ic0 + j)*5 + tap];
        _Float16 hi = (_Float16)w;
        w2h[(size_t)i*8 + j] = hi;
        w2l[(size_t)i*8 + j] = (_Float16)(w - (float)hi);
      }
    }
  }
  {
    _Float16* w3h = (_Float16*)(ws + OFF_W3H);
    _Float16* w3l = (_Float16*)(ws + OFF_W3L);
    for (int i = tid; i < 28*2*64; i += nt) {
      int lane = i & 63, ot = (i >> 6) & 1, sk = i >> 7;
      int tap = sk >> 2, ic0 = (sk & 3)*16 + (lane >> 5)*8;
      int o = ot*32 + (lane & 31);
      #pragma unroll
      for (int j = 0; j < 8; ++j) {
        float w = conv3_w[o*448 + (ic0 + j)*7 + tap];
        _Float16 hi = (_Float16)w;
        w3h[(size_t)i*8 + j] = hi;
        w3l[(size_t)i*8 + j] = (_Float16)(w - (float)hi);
      }
    }
  }
  // PB[c][j] = sum_m proj_w[c][m]*Bm[m][j]
  for (int i = tid; i < 64; i += nt) {
    int c = i >> 4, j = i & 15;
    float acc = 0.f;
    for (int m = 0; m < 64; ++m) acc += proj_w[c*64+m]*Bm[m*16+j];
    ws[OFF_PB + i] = acc;
  }
  for (int j = tid; j < 16; j += nt) {
    float acc = 0.f;
    for (int m = 0; m < 64; ++m) acc += proj_b[m]*Bm[m*16+j];
    ws[OFF_PBB + j] = acc;
  }
  // CO[j][o] = sum_m Cm[j][m]*out_w[m][o]
  for (int i = tid; i < 16*64; i += nt) {
    int j = i >> 6, o = i & 63;
    float acc = 0.f;
    for (int m = 0; m < 64; ++m) acc += Cm[j*64+m]*out_w[m*64+o];
    ws[OFF_CO + i] = acc;
  }
}

// ============================ conv stack ============================
// Roles: waves 0-1 = c2 (w2 hi+lo in regs, ot=wid, 2 pairs);
//        waves 2-5 = c3 (w3 hi in regs, lo from LDS; (ot,pair) split; +conv1).
// Pipeline per iter: Seg1: c3 conv1(g), c2 conv2-pair1(g-1);
//                    Seg2: c2 conv2-pair0(g), c3 conv3(g-1) -> sf.
// CRITICAL (r3-r5 lesson): both roles' weight arrays must share ONE union
// array `wreg` — separate w2h/w2l/w3h arrays are all statically live in every
// wave (uniform-but-runtime branch), peak 272 VGPR > 256 -> wholesale scratch
// spill (VGPR_Count=128, 530 MB spill traffic, 338 us).
__global__ __launch_bounds__(384) void conv_kernel(
    const float* __restrict__ x, const float* __restrict__ wsr,
    float* __restrict__ sfp)
{
  __shared__ __align__(16) _Float16 a1h[2][4*AS];
  __shared__ __align__(16) _Float16 a1l[2][4*AS];
  __shared__ __align__(16) _Float16 a2h[2][4*AS];
  __shared__ __align__(16) _Float16 a2l[2][4*AS];
  __shared__ __align__(16) _Float16 w3ls[28*2*64*8];   // 57344 B

  const int tid = threadIdx.x;
  const int lane = tid & 63;
  const int wid = tid >> 6;
  const bool isC2 = (wid < 2);
  const int n = lane & 15;
  const int nc = (n < 10) ? n : 9;       // clamp; junk cols masked in epilogue
  const int kh8 = (lane >> 5) * 8;

  // zero acts (pads rely on this; valid slots rewritten per group)
  for (int i = tid; i < 4*AS; i += 384) {
    ((unsigned*)a1h)[i] = 0u; ((unsigned*)a1l)[i] = 0u;
    ((unsigned*)a2h)[i] = 0u; ((unsigned*)a2l)[i] = 0u;
  }
  // stage w3-lo fragments into LDS (layout identical to ws image)
  {
    const f32x4* src = (const f32x4*)(wsr + OFF_W3L);
    f32x4* dst = (f32x4*)w3ls;
    for (int i = tid; i < 14336/4; i += 384) dst[i] = src[i];
  }

  // ---- unified weight register file (160 VGPRs), role-dependent contents:
  //   c2 waves: wreg[0..19] = w2h, wreg[20..39] = w2l
  //   c3 waves: wreg[0..27] = w3h (lo streamed from w3ls)
  half8 wreg[40];
  float w1c[12], sc1 = 0.f, sh1 = 0.f;
  int ot3 = 0, p3 = 0, lb3 = 0, idx3 = 0;

  if (isC2) {
    const int ot = wid;
    #pragma unroll
    for (int sk = 0; sk < 20; ++sk) {
      wreg[sk]      = *(const half8*)(wsr + OFF_W2H + (size_t)((sk*2 + ot)*64 + lane)*4);
      wreg[20 + sk] = *(const half8*)(wsr + OFF_W2L + (size_t)((sk*2 + ot)*64 + lane)*4);
    }
  } else {
    idx3 = wid - 2;
    ot3 = idx3 & 1;
    p3 = idx3 >> 1;
    lb3 = 2*p3 + ((lane >> 4) & 1);
    #pragma unroll
    for (int sk = 0; sk < 28; ++sk)
      wreg[sk] = *(const half8*)(wsr + OFF_W3H + (size_t)((sk*2 + ot3)*64 + lane)*4);
    #pragma unroll
    for (int i = 0; i < 12; ++i) w1c[i] = wsr[OFF_W1T + i*64 + lane];
    sc1 = wsr[OFF_SC1 + lane]; sh1 = wsr[OFF_SH1 + lane];
  }
  const int rq2 = 4*(lane >> 5) + wid*32;        // c2 row base (ot=wid)
  const int rq3 = 4*(lane >> 5) + ot3*32;        // c3 row base

  __syncthreads();

  // c2 conv2 for one pair of one group
  auto conv2_pair = [&](int abuf, int bbuf, int p, int g) {
    const int lb = 2*p + ((lane >> 4) & 1);
    const _Float16* bhp = &a1h[abuf][lb*AS];
    const _Float16* blp = &a1l[abuf][lb*AS];
    f32x16 acc;
    #pragma unroll
    for (int r = 0; r < 16; ++r) acc[r] = 0.f;
    #pragma unroll
    for (int sk = 0; sk < 20; ++sk) {
      const int tap = sk >> 2, icb = (sk & 3)*16;
      const int off = (nc + tap + 1)*72 + icb + kh8;
      const half8 bh = *(const half8*)(bhp + off);
      const half8 bl = *(const half8*)(blp + off);
      acc = mfma16(wreg[sk], bh, acc);
      acc = mfma16(wreg[sk], bl, acc);
      acc = mfma16(wreg[20 + sk], bh, acc);
    }
    if (n < 10) {
      #pragma unroll
      for (int q = 0; q < 4; ++q) {
        const int rowb = 8*q + rq2;
        const f32x4 sc = *(const f32x4*)(wsr + OFF_SC2 + rowb);
        const f32x4 sh = *(const f32x4*)(wsr + OFF_SH2 + rowb);
        half4 h4, l4;
        #pragma unroll
        for (int r = 0; r < 4; ++r) {
          float v = sc[r]*acc[4*q + r] + sh[r];
          v = v > 0.f ? v : 0.f;
          _Float16 hi = (_Float16)v;
          h4[r] = hi;
          l4[r] = (_Float16)(v - (float)hi);
        }
        *(half4*)(&a2h[bbuf][lb*AS + (n + 3)*72 + rowb]) = h4;
        *(half4*)(&a2l[bbuf][lb*AS + (n + 3)*72 + rowb]) = l4;
      }
    }
  };

  for (int it = 0; it <= NGRP; ++it) {
    const int g = blockIdx.x*NGRP + it;
    const int cb = it & 1;       // buffers for group g
    // ---------------- Seg1 ----------------
    if (isC2) {
      if (it > 0) conv2_pair(cb ^ 1, cb ^ 1, 1, g - 1);
    } else {
      if (it < NGRP) {
        // conv1 for batch g*4 + idx3 (fp32 VALU, lane = out channel)
        const size_t bi = (size_t)g*4 + idx3;
        float xv[4][12];
        #pragma unroll
        for (int c = 0; c < 4; ++c) { xv[c][0] = 0.f; xv[c][11] = 0.f; }
        #pragma unroll
        for (int tt = 0; tt < 10; ++tt)
          #pragma unroll
          for (int c = 0; c < 4; ++c)
            xv[c][1 + tt] = x[bi*400 + (90 + tt)*4 + c];
        float a1[10];
        #pragma unroll
        for (int t = 0; t < 10; ++t) a1[t] = 0.f;
        #pragma unroll
        for (int c = 0; c < 4; ++c)
          #pragma unroll
          for (int k = 0; k < 3; ++k) {
            const float wv = w1c[c*3 + k];
            #pragma unroll
            for (int t = 0; t < 10; ++t) a1[t] += wv * xv[c][t + k];
          }
        #pragma unroll
        for (int t = 0; t < 10; ++t) {
          float v = sc1*a1[t] + sh1;
          v = v > 0.f ? v : 0.f;
          _Float16 hi = (_Float16)v;
          a1h[cb][idx3*AS + (3 + t)*72 + lane] = hi;
          a1l[cb][idx3*AS + (3 + t)*72 + lane] = (_Float16)(v - (float)hi);
        }
      }
    }
    __syncthreads();
    // ---------------- Seg2 ----------------
    if (isC2) {
      if (it < NGRP) conv2_pair(cb, cb, 0, g);
    } else {
      if (it > 0) {
        const int rb = cb ^ 1;   // act2 buffer of group g-1
        const _Float16* bhp = &a2h[rb][lb3*AS];
        const _Float16* blp = &a2l[rb][lb3*AS];
        f32x16 acc;
        #pragma unroll
        for (int r = 0; r < 16; ++r) acc[r] = 0.f;
        #pragma unroll
        for (int sk = 0; sk < 28; ++sk) {
          const int tap = sk >> 2, icb = (sk & 3)*16;
          const int off = (nc + tap)*72 + icb + kh8;
          const half8 bh = *(const half8*)(bhp + off);
          const half8 bl = *(const half8*)(blp + off);
          const half8 wl = *(const half8*)(w3ls + ((size_t)(sk*2 + ot3)*64 + lane)*8);
          acc = mfma16(wreg[sk], bh, acc);
          acc = mfma16(wreg[sk], bl, acc);
          acc = mfma16(wl, bh, acc);
        }
        #pragma unroll
        for (int q = 0; q < 4; ++q) {
          const int rowb = 8*q + rq3;
          const f32x4 sc = *(const f32x4*)(wsr + OFF_SC3 + rowb);
          const f32x4 sh = *(const f32x4*)(wsr + OFF_SH3 + rowb);
          f32x4 v;
          #pragma unroll
          for (int r = 0; r < 4; ++r) {
            float t = sc[r]*acc[4*q + r] + sh[r];
            t = t > 0.f ? t : 0.f;
            v[r] = (n < 10) ? t : 0.f;
          }
          #pragma unroll
          for (int r = 0; r < 4; ++r) {
            v[r] += __shfl_xor(v[r], 1, 16);
            v[r] += __shfl_xor(v[r], 2, 16);
            v[r] += __shfl_xor(v[r], 4, 16);
            v[r] += __shfl_xor(v[r], 8, 16);
          }
          if (n == 0)
            *(f32x4*)(sfp + ((size_t)(g - 1)*4 + lb3)*64 + rowb) = v * 0.1f;
        }
      }
    }
    __syncthreads();
  }
}

// ============================ RNN ============================
__global__ __launch_bounds__(256) void rnn_kernel(
    const float* __restrict__ x, const float* __restrict__ wsr,
    const float* __restrict__ A, float* __restrict__ hout)
{
  __shared__ float hbuf[16][20];   // padded rows; 16 groups per block
  int tid = blockIdx.x * 256 + threadIdx.x;
  int b = tid >> 4;
  int j = tid & 15;
  int g = threadIdx.x >> 4;

  float Arow[16];
  const float4* Ap = (const float4*)(A + j*16);
  #pragma unroll
  for (int q = 0; q < 4; ++q) { float4 v = Ap[q]; Arow[4*q]=v.x; Arow[4*q+1]=v.y; Arow[4*q+2]=v.z; Arow[4*q+3]=v.w; }
  float pb0 = wsr[OFF_PB + 0*16 + j];
  float pb1 = wsr[OFF_PB + 1*16 + j];
  float pb2 = wsr[OFF_PB + 2*16 + j];
  float pb3 = wsr[OFF_PB + 3*16 + j];
  float biasv = wsr[OFF_PBB + j];

  const float4* xb = (const float4*)(x + (size_t)b*400);
  float h = 0.f;
  float4 cur[5], nxt[5];
  #pragma unroll
  for (int q = 0; q < 5; ++q) cur[q] = xb[q];
  for (int tc = 0; tc < 100; tc += 5) {
    if (tc + 5 < 100) {
      #pragma unroll
      for (int q = 0; q < 5; ++q) nxt[q] = xb[tc+5+q];
    }
    #pragma unroll
    for (int q = 0; q < 5; ++q) {
      float4 cx = cur[q];
      float u = biasv + cx.x*pb0 + cx.y*pb1 + cx.z*pb2 + cx.w*pb3;
      hbuf[g][j] = h;                       // same-wave LDS broadcast
      const f32x4* hp = (const f32x4*)hbuf[g];
      #pragma unroll
      for (int qq = 0; qq < 4; ++qq) {
        f32x4 hv = hp[qq];
        u += hv[0]*Arow[4*qq] + hv[1]*Arow[4*qq+1] + hv[2]*Arow[4*qq+2] + hv[3]*Arow[4*qq+3];
      }
      float e = __expf(2.f*u);
      h = 1.f - 2.f/(e + 1.f);
    }
    #pragma unroll
    for (int q = 0; q < 5; ++q) cur[q] = nxt[q];
  }
  hout[(size_t)b*16 + j] = h;
}

// ============================ tail ============================
// lane = (b4 = lane>>4, og = lane&15): 4 batches/wave, o-quad per lane.
// All stage buffers are wave-private per (wid) -> no in-loop barriers.
__global__ __launch_bounds__(256) void tail_kernel(
    const float* __restrict__ wsr,
    const float* __restrict__ g1_w, const float* __restrict__ g1_b,
    const float* __restrict__ g2_w, const float* __restrict__ g2_b,
    const float* __restrict__ h1_w, const float* __restrict__ h1_b,
    const float* __restrict__ h2_w, const float* __restrict__ h2_b,
    const float* __restrict__ out_b, float* __restrict__ out)
{
  __shared__ float sG1[128*64];   // 32 KB, [k][o]
  __shared__ float sG2[64*64];    // 16 KB
  __shared__ float sH1[64*32];    // 8 KB
  __shared__ float sH2[32*3];
  __shared__ float sCO[16*64];    // 4 KB
  __shared__ float wbuf[16][132];
  __shared__ float tbuf[16][68];
  __shared__ float t2buf[16][36];
  __shared__ float hbuf[4][64];
  int tid = threadIdx.x;
  for (int i = tid; i < 128*64; i += 256) sG1[i] = g1_w[i];
  for (int i = tid; i < 64*64; i += 256) sG2[i] = g2_w[i];
  for (int i = tid; i < 64*32; i += 256) sH1[i] = h1_w[i];
  for (int i = tid; i < 96; i += 256) sH2[i] = h2_w[i];
  for (int i = tid; i < 16*64; i += 256) sCO[i] = wsr[OFF_CO + i];
  __syncthreads();

  const int lane = tid & 63, wid = tid >> 6;
  const int b4 = lane >> 4, og = lane & 15;
  const int wb = wid*4 + b4;
  const float* sf = wsr + OFF_SF;
  const float* hws = wsr + OFF_H;
  const f32x4 g1b4 = *(const f32x4*)(g1_b + 4*og);
  const f32x4 g2b4 = *(const f32x4*)(g2_b + 4*og);
  const f32x4 ob4  = *(const f32x4*)(out_b + 4*og);
  const f32x2 h1b2 = *(const f32x2*)(h1_b + 2*og);
  const float h2bv = (og < 3) ? h2_b[og] : 0.f;

  for (int seg = 0; seg < 4; ++seg) {
    const int wq = blockIdx.x*64 + seg*16 + wid*4;
    const int batch = wq + b4;
    hbuf[wid][lane] = hws[(size_t)wq*16 + lane];
    const f32x4 sfv = *(const f32x4*)(sf + (size_t)batch*64 + 4*og);
    f32x4 lcv = ob4;
    #pragma unroll
    for (int j = 0; j < 16; ++j) {
      const float hj = hbuf[wid][b4*16 + j];
      const f32x4 co = *(const f32x4*)(sCO + j*64 + 4*og);
      lcv += hj * co;
    }
    *(f32x4*)(&wbuf[wb][4*og]) = sfv;
    *(f32x4*)(&wbuf[wb][64 + 4*og]) = lcv;
    // L1: combined(128) @ g1 -> tanh
    f32x4 u = g1b4;
    #pragma unroll 8
    for (int k = 0; k < 128; ++k)
      u += wbuf[wb][k] * *(const f32x4*)(sG1 + k*64 + 4*og);
    f32x4 t1;
    #pragma unroll
    for (int r = 0; r < 4; ++r) {
      float e = __expf(2.f*u[r]);
      t1[r] = 1.f - 2.f/(e + 1.f);
    }
    *(f32x4*)(&tbuf[wb][4*og]) = t1;
    // L2: t1(64) @ g2 -> sigmoid -> gate
    f32x4 u2 = g2b4;
    #pragma unroll 8
    for (int k = 0; k < 64; ++k)
      u2 += tbuf[wb][k] * *(const f32x4*)(sG2 + k*64 + 4*og);
    f32x4 filt;
    #pragma unroll
    for (int r = 0; r < 4; ++r)
      filt[r] = sfv[r] / (1.f + __expf(-u2[r]));
    *(f32x4*)(&wbuf[wb][4*og]) = filt;
    // L3: filt(64) @ h1 -> relu (32 outs: 2 per lane)
    f32x2 r2 = h1b2;
    #pragma unroll 8
    for (int k = 0; k < 64; ++k)
      r2 += wbuf[wb][k] * *(const f32x2*)(sH1 + k*32 + 2*og);
    r2[0] = fmaxf(r2[0], 0.f); r2[1] = fmaxf(r2[1], 0.f);
    *(f32x2*)(&t2buf[wb][2*og]) = r2;
    // L4: (32) @ h2 -> 3 logits
    if (og < 3) {
      float a = h2bv;
      #pragma unroll
      for (int k = 0; k < 32; ++k) a += t2buf[wb][k] * sH2[k*3 + og];
      out[(size_t)batch*3 + og] = a;
    }
  }
}

// ============================ launch ============================
extern "C" void kernel_launch(void* const* d_in, const int* in_sizes, int n_in,
                              void* d_out, int out_size, void* d_ws, size_t ws_size,
                              hipStream_t stream) {
  const float* x       = (const float*)d_in[0];
  const float* conv1_w = (const float*)d_in[1];
  const float* conv1_b = (const float*)d_in[2];
  const float* conv2_w = (const float*)d_in[3];
  const float* conv2_b = (const float*)d_in[4];
  const float* conv3_w = (const float*)d_in[5];
  const float* conv3_b = (const float*)d_in[6];
  const float* bn1_g   = (const float*)d_in[7];
  const float* bn1_b   = (const float*)d_in[8];
  const float* bn2_g   = (const float*)d_in[9];
  const float* bn2_b   = (const float*)d_in[10];
  const float* bn3_g   = (const float*)d_in[11];
  const float* bn3_b   = (const float*)d_in[12];
  const float* proj_w  = (const float*)d_in[13];
  const float* proj_b  = (const float*)d_in[14];
  const float* A       = (const float*)d_in[15];
  const float* Bm      = (const float*)d_in[16];
  const float* Cm      = (const float*)d_in[17];
  const float* out_w   = (const float*)d_in[18];
  const float* out_b   = (const float*)d_in[19];
  const float* g1_w    = (const float*)d_in[20];
  const float* g1_b    = (const float*)d_in[21];
  const float* g2_w    = (const float*)d_in[22];
  const float* g2_b    = (const float*)d_in[23];
  const float* h1_w    = (const float*)d_in[24];
  const float* h1_b    = (const float*)d_in[25];
  const float* h2_w    = (const float*)d_in[26];
  const float* h2_b    = (const float*)d_in[27];
  float* ws = (float*)d_ws;
  float* out = (float*)d_out;

  prep_kernel<<<64, 256, 0, stream>>>(conv1_w, conv1_b, conv2_w, conv2_b,
      conv3_w, conv3_b, bn1_g, bn1_b, bn2_g, bn2_b, bn3_g, bn3_b,
      proj_w, proj_b, A, Bm, Cm, out_w, ws);
  conv_kernel<<<NB/(4*NGRP), 384, 0, stream>>>(x, ws, ws + OFF_SF);
  rnn_kernel<<<NB*16/256, 256, 0, stream>>>(x, ws, A, ws + OFF_H);
  tail_kernel<<<NB/64, 256, 0, stream>>>(ws, g1_w, g1_b, g2_w, g2_b,
      h1_w, h1_b, h2_w, h2_b, out_b, out);
}